// Round 13
// baseline (278.629 us; speedup 1.0000x reference)
//
#include <hip/hip_runtime.h>
#include <hip/hip_bf16.h>
#include <hip/hip_fp16.h>

#define N_NODES 50000
#define N_EDGES 640000
#define N_GRAPHS 500
#define D 128
#define CAP 64   // neighbor slots per node; P(Poisson(12.8) > 64) ~ 1e-30

#define PREP_X_BLOCKS (N_NODES * D / 8 / 256) // 3125 (exact)
#define PREP_E_BLOCKS (N_EDGES / 256)         // 2500 (exact), 1 edge/thread
#define PREP_W_BLOCKS (6 * D * D / 256)       // 384 (exact)

typedef _Float16 h8_t __attribute__((ext_vector_type(8)));   // 8 fp16 = 4 VGPRs
typedef __attribute__((ext_vector_type(4))) float f4_t;

// ---------------------------------------------------------------------------
// prep: (a) binned-CSR fill (1 edge/thread; atomic-rate-bound at ~6/cyc),
//       (b) x fp32->fp16, (c) W (L,K,N) fp32 -> fp16 transposed (L,N,K).
// ---------------------------------------------------------------------------
__global__ __launch_bounds__(256) void gin_prep_kernel(
    const float* __restrict__ x, _Float16* __restrict__ xh,
    const int* __restrict__ src, const int* __restrict__ dst,
    int* __restrict__ cnt, int* __restrict__ slots,
    const float* __restrict__ W1, const float* __restrict__ W2,
    _Float16* __restrict__ Wt1, _Float16* __restrict__ Wt2)
{
    const int b = blockIdx.x, t = threadIdx.x;
    if (b < PREP_E_BLOCKS) {
        int e = b * 256 + t;                       // one edge per thread
        int s = src[e];
        int d = dst[e];
        int sl = atomicAdd(&cnt[d], 1);
        if (sl < CAP) slots[(d << 6) + sl] = s;
    } else if (b < PREP_E_BLOCKS + PREP_X_BLOCKS) {
        int i = (b - PREP_E_BLOCKS) * 256 + t;     // h8-unit index
        const float4* p = (const float4*)x;
        float4 v0 = p[2 * i], v1 = p[2 * i + 1];
        h8_t o;
        o[0] = (_Float16)v0.x; o[1] = (_Float16)v0.y;
        o[2] = (_Float16)v0.z; o[3] = (_Float16)v0.w;
        o[4] = (_Float16)v1.x; o[5] = (_Float16)v1.y;
        o[6] = (_Float16)v1.z; o[7] = (_Float16)v1.w;
        ((h8_t*)xh)[i] = o;
    } else {
        int idx = (b - PREP_E_BLOCKS - PREP_X_BLOCKS) * 256 + t;
        int m = idx >> 14;
        int r = idx & 16383;
        int n = r >> 7, k = r & 127;
        const float* srcw = (m < 3) ? (W1 + ((long)m << 14)) : (W2 + ((long)(m - 3) << 14));
        _Float16* dstw = (m < 3) ? (Wt1 + ((long)m << 14)) : (Wt2 + ((long)(m - 3) << 14));
        dstw[(n << 7) | k] = (_Float16)srcw[(k << 7) | n];   // Wt[n][k] = W[k][n]
    }
}

// ---------------------------------------------------------------------------
// FUSED LAYER v6: out = relu(BN(relu((x_self + sum_n x) @ W1 + b1) @ W2 + b2))
// Block = 512 thr (8 waves) owns 32 nodes; grid 1563.
//  phase G (SOFTWARE-PIPELINED wave-per-node): each iteration a wave issues
//   node A's 17 row-loads AND node B's 17 (34 rows in flight — r12's VGPR=32
//   allowed only one window, exposing a full drain per node), then consumes A
//   (partial vmcnt wait), then B. launch_bounds(512,8) -> ~64 VGPR budget so
//   both windows live in registers. Residual loops handle deg>16 (~15%).
//   DOUBLE accumulation: fp16 vals are multiples of 2^-24, |v|<2^6, deg<2^6
//   -> sums EXACT -> bit-identical for ANY slot order (atomics vary per call).
//  stage 1: a_s @ W1 (MFMA), h=relu(+b1) back into a_s.
//  stage 2: out = relu(BN(a_s @ W2 + b2)) -> global.
// in/out must differ (caller ping-pongs).
// ---------------------------------------------------------------------------
constexpr int ASTR = 136;   // fp16 elems/row in LDS: +8 pad

__device__ __forceinline__ float2 unpack_h2(unsigned v) {
    __half2 h = __builtin_bit_cast(__half2, v);
    return __half22float2(h);
}

__global__ __launch_bounds__(512, 8) void gin_layer_kernel(
    const _Float16* __restrict__ x,
    const int* __restrict__ cnt, const int* __restrict__ slots,
    const _Float16* __restrict__ Wt1, const float* __restrict__ b1,
    const _Float16* __restrict__ Wt2, const float* __restrict__ b2,
    const float* __restrict__ bn_scale, const float* __restrict__ bn_bias,
    const float* __restrict__ bn_mean, const float* __restrict__ bn_var,
    _Float16* __restrict__ out, int N)
{
    __shared__ __align__(16) _Float16 a_s[32 * ASTR];
    __shared__ float ep_a[D], ep_b[D], b1_s[D];

    const int tid = threadIdx.x;
    if (tid < D) {
        float s = bn_scale[tid] * rsqrtf(bn_var[tid] + 1e-5f);
        ep_a[tid] = s;
        ep_b[tid] = (b2[tid] - bn_mean[tid]) * s + bn_bias[tid];
        b1_s[tid] = b1[tid];
    }

    const int row0 = blockIdx.x * 32;
    const int lane = tid & 63;
    const int wave_u = __builtin_amdgcn_readfirstlane(tid >> 6);   // 0..7, SGPR
    const unsigned* __restrict__ xw = (const unsigned*)x;          // dword = 2 fp16

    // ---- phase G: pipelined A/B wave-per-node gather ----
    #pragma unroll 1
    for (int pp = 0; pp < 2; ++pp) {
        const int nlA = pp * 16 + wave_u;          // 0..7 / 16..23
        const int nlB = nlA + 8;                   // 8..15 / 24..31
        const int nodeA = row0 + nlA;
        const int nodeB = row0 + nlB;
        const bool liveA = (nodeA < N), liveB = (nodeB < N);
        const int cntA = liveA ? __builtin_amdgcn_readfirstlane(cnt[nodeA]) : 0;
        const int cntB = liveB ? __builtin_amdgcn_readfirstlane(cnt[nodeB]) : 0;
        const int* cpA = slots + ((long)nodeA << 6);   // uniform base -> s_loads
        const int* cpB = slots + ((long)nodeB << 6);

        // ---- issue phase: A's 17 rows, then B's 17 (34 in flight) ----
        unsigned sA = 0, sB = 0, vA[16], vB[16];
        if (liveA) {
            int idx[16];
            #pragma unroll
            for (int i = 0; i < 16; ++i) idx[i] = cpA[i];          // s_loads
            sA = xw[(long)nodeA * 64 + lane];
            #pragma unroll
            for (int i = 0; i < 16; ++i) {
                int j = (i < cntA) ? idx[i] : 0;                   // scalar select
                vA[i] = xw[(long)j * 64 + lane];                   // coalesced 256B
            }
        }
        if (liveB) {
            int idx[16];
            #pragma unroll
            for (int i = 0; i < 16; ++i) idx[i] = cpB[i];
            sB = xw[(long)nodeB * 64 + lane];
            #pragma unroll
            for (int i = 0; i < 16; ++i) {
                int j = (i < cntB) ? idx[i] : 0;
                vB[i] = xw[(long)j * 64 + lane];
            }
        }

        // ---- consume A (waits only on A's loads; B stays in flight) ----
        {
            double a0 = 0.0, a1 = 0.0, c0 = 0.0, c1 = 0.0;
            if (liveA) {
                float2 f = unpack_h2(sA);
                a0 = (double)f.x; a1 = (double)f.y;
                #pragma unroll
                for (int i = 0; i < 16; i += 2) {                  // 2-way f64 ILP
                    unsigned m0 = (i < cntA) ? vA[i] : 0u;
                    unsigned m1 = (i + 1 < cntA) ? vA[i + 1] : 0u;
                    float2 g0 = unpack_h2(m0);
                    float2 g1 = unpack_h2(m1);
                    a0 += (double)g0.x; a1 += (double)g0.y;
                    c0 += (double)g1.x; c1 += (double)g1.y;
                }
                #pragma unroll 1
                for (int k = 16; k < cntA; k += 8) {               // residual ~15%
                    unsigned vv[8];
                    #pragma unroll
                    for (int i = 0; i < 8; ++i) {
                        int kk = k + i;
                        int j = (kk < cntA) ? cpA[kk] : 0;
                        vv[i] = xw[(long)j * 64 + lane];
                    }
                    #pragma unroll
                    for (int i = 0; i < 8; i += 2) {
                        unsigned m0 = (k + i < cntA) ? vv[i] : 0u;
                        unsigned m1 = (k + i + 1 < cntA) ? vv[i + 1] : 0u;
                        float2 g0 = unpack_h2(m0);
                        float2 g1 = unpack_h2(m1);
                        a0 += (double)g0.x; a1 += (double)g0.y;
                        c0 += (double)g1.x; c1 += (double)g1.y;
                    }
                }
            }
            _Float16 h0 = (_Float16)(float)(a0 + c0);
            _Float16 h1 = (_Float16)(float)(a1 + c1);
            unsigned pk = (unsigned)__builtin_bit_cast(unsigned short, h0) |
                          ((unsigned)__builtin_bit_cast(unsigned short, h1) << 16);
            *(unsigned*)(a_s + nlA * ASTR + lane * 2) = pk;
        }

        // ---- consume B ----
        {
            double a0 = 0.0, a1 = 0.0, c0 = 0.0, c1 = 0.0;
            if (liveB) {
                float2 f = unpack_h2(sB);
                a0 = (double)f.x; a1 = (double)f.y;
                #pragma unroll
                for (int i = 0; i < 16; i += 2) {
                    unsigned m0 = (i < cntB) ? vB[i] : 0u;
                    unsigned m1 = (i + 1 < cntB) ? vB[i + 1] : 0u;
                    float2 g0 = unpack_h2(m0);
                    float2 g1 = unpack_h2(m1);
                    a0 += (double)g0.x; a1 += (double)g0.y;
                    c0 += (double)g1.x; c1 += (double)g1.y;
                }
                #pragma unroll 1
                for (int k = 16; k < cntB; k += 8) {
                    unsigned vv[8];
                    #pragma unroll
                    for (int i = 0; i < 8; ++i) {
                        int kk = k + i;
                        int j = (kk < cntB) ? cpB[kk] : 0;
                        vv[i] = xw[(long)j * 64 + lane];
                    }
                    #pragma unroll
                    for (int i = 0; i < 8; i += 2) {
                        unsigned m0 = (k + i < cntB) ? vv[i] : 0u;
                        unsigned m1 = (k + i + 1 < cntB) ? vv[i + 1] : 0u;
                        float2 g0 = unpack_h2(m0);
                        float2 g1 = unpack_h2(m1);
                        a0 += (double)g0.x; a1 += (double)g0.y;
                        c0 += (double)g1.x; c1 += (double)g1.y;
                    }
                }
            }
            _Float16 h0 = (_Float16)(float)(a0 + c0);
            _Float16 h1 = (_Float16)(float)(a1 + c1);
            unsigned pk = (unsigned)__builtin_bit_cast(unsigned short, h0) |
                          ((unsigned)__builtin_bit_cast(unsigned short, h1) << 16);
            *(unsigned*)(a_s + nlB * ASTR + lane * 2) = pk;
        }
    }
    __syncthreads();

    // ---- stage 1: a_s @ W1 ----  (wave w -> col tile [16w,16w+16), rows 0..31)
    const int m16 = lane & 15;
    const int kq  = lane >> 4;
    const int coln = wave_u * 16 + m16;

    f4_t a1m[2] = {(f4_t){0.f, 0.f, 0.f, 0.f}, (f4_t){0.f, 0.f, 0.f, 0.f}};
    #pragma unroll
    for (int kc = 0; kc < 4; ++kc) {
        const int k0 = kc * 32 + kq * 8;
        h8_t af0 = *(const h8_t*)(a_s + m16 * ASTR + k0);
        h8_t af1 = *(const h8_t*)(a_s + (16 + m16) * ASTR + k0);
        h8_t bf  = *(const h8_t*)(Wt1 + (long)coln * D + k0);
        a1m[0] = __builtin_amdgcn_mfma_f32_16x16x32_f16(af0, bf, a1m[0], 0, 0, 0);
        a1m[1] = __builtin_amdgcn_mfma_f32_16x16x32_f16(af1, bf, a1m[1], 0, 0, 0);
    }
    __syncthreads();   // all a_s reads done -> safe to overwrite

    // h = relu(a1m + b1) back into a_s  (C/D: col=m16, row=kq*4+g)
    {
        const float bb = b1_s[coln];
        #pragma unroll
        for (int r = 0; r < 2; ++r)
            #pragma unroll
            for (int g = 0; g < 4; ++g) {
                float vv = fmaxf(a1m[r][g] + bb, 0.f);
                a_s[(r * 16 + kq * 4 + g) * ASTR + coln] = (_Float16)vv;
            }
    }
    __syncthreads();

    // ---- stage 2: out = relu(BN(a_s @ W2 + b2)) ----
    f4_t a2m[2] = {(f4_t){0.f, 0.f, 0.f, 0.f}, (f4_t){0.f, 0.f, 0.f, 0.f}};
    #pragma unroll
    for (int kc = 0; kc < 4; ++kc) {
        const int k0 = kc * 32 + kq * 8;
        h8_t af0 = *(const h8_t*)(a_s + m16 * ASTR + k0);
        h8_t af1 = *(const h8_t*)(a_s + (16 + m16) * ASTR + k0);
        h8_t bf  = *(const h8_t*)(Wt2 + (long)coln * D + k0);
        a2m[0] = __builtin_amdgcn_mfma_f32_16x16x32_f16(af0, bf, a2m[0], 0, 0, 0);
        a2m[1] = __builtin_amdgcn_mfma_f32_16x16x32_f16(af1, bf, a2m[1], 0, 0, 0);
    }
    {
        const float ea = ep_a[coln], eb = ep_b[coln];
        #pragma unroll
        for (int r = 0; r < 2; ++r) {
            const int rb = row0 + r * 16 + kq * 4;
            #pragma unroll
            for (int g = 0; g < 4; ++g) {
                const int grow = rb + g;
                if (grow < N) {
                    float vv = fmaxf(fmaf(a2m[r][g], ea, eb), 0.f);
                    out[(long)grow * D + coln] = (_Float16)vv;
                }
            }
        }
    }
}

// ---------------------------------------------------------------------------
// fused pool+head: one block (128 thr) per graph. batch sorted -> binary
// search; fixed-order fp32 sum -> deterministic.
// ---------------------------------------------------------------------------
__global__ __launch_bounds__(128) void gin_poolhead_kernel(
    const _Float16* __restrict__ x, const int* __restrict__ batch,
    const float* __restrict__ Wh1, const float* __restrict__ bh1,
    const float* __restrict__ Wh2, const float* __restrict__ bh2,
    float* __restrict__ out, int N)
{
    const int gid = blockIdx.x;
    const int t = threadIdx.x;
    __shared__ float gs[D];
    __shared__ float hid[64];

    int lo = 0, hi = N;
    while (lo < hi) { int m = (lo + hi) >> 1; if (batch[m] < gid) lo = m + 1; else hi = m; }
    int s = lo;
    hi = N;
    while (lo < hi) { int m = (lo + hi) >> 1; if (batch[m] < gid + 1) lo = m + 1; else hi = m; }
    int e = lo;
    float a0 = 0.f, a1 = 0.f, a2 = 0.f, a3 = 0.f;
    int i = s;
    for (; i + 4 <= e; i += 4) {
        a0 += (float)x[(long)i * D + t];
        a1 += (float)x[(long)(i + 1) * D + t];
        a2 += (float)x[(long)(i + 2) * D + t];
        a3 += (float)x[(long)(i + 3) * D + t];
    }
    for (; i < e; ++i) a0 += (float)x[(long)i * D + t];
    gs[t] = (a0 + a1) + (a2 + a3);
    __syncthreads();

    if (t < 64) {
        float acc = bh1[t];
        #pragma unroll 4
        for (int k = 0; k < D; ++k) acc = fmaf(gs[k], Wh1[k * 64 + t], acc);
        hid[t] = fmaxf(acc, 0.f);
    }
    __syncthreads();
    if (t < 12) {
        float acc2 = bh2[t];
        #pragma unroll 4
        for (int j = 0; j < 64; ++j) acc2 = fmaf(hid[j], Wh2[j * 12 + t], acc2);
        out[gid * 12 + t] = 1.f / (1.f + __expf(-acc2));
    }
}

// ---------------------------------------------------------------------------
extern "C" void kernel_launch(void* const* d_in, const int* in_sizes, int n_in,
                              void* d_out, int out_size, void* d_ws, size_t ws_size,
                              hipStream_t stream) {
    const float* x    = (const float*)d_in[0];
    const int*   edge = (const int*)d_in[1];
    const int*   batch= (const int*)d_in[2];
    const float* W1   = (const float*)d_in[3];
    const float* b1   = (const float*)d_in[4];
    const float* W2   = (const float*)d_in[5];
    const float* b2   = (const float*)d_in[6];
    const float* bns  = (const float*)d_in[7];
    const float* bnb  = (const float*)d_in[8];
    const float* bnm  = (const float*)d_in[9];
    const float* bnv  = (const float*)d_in[10];
    const float* Wh1  = (const float*)d_in[11];
    const float* bh1  = (const float*)d_in[12];
    const float* Wh2  = (const float*)d_in[13];
    const float* bh2  = (const float*)d_in[14];
    float* outp = (float*)d_out;

    const int* esrc = edge;
    const int* edst = edge + N_EDGES;

    char* ws = (char*)d_ws;
    size_t off = 0;
    auto alloc = [&](size_t bytes) -> void* {
        void* p = ws + off;
        off += (bytes + 255) & ~(size_t)255;
        return p;
    };
    _Float16* x_h   = (_Float16*)alloc((size_t)N_NODES * D * 2);
    _Float16* bufA  = (_Float16*)alloc((size_t)N_NODES * D * 2);
    _Float16* bufB  = (_Float16*)alloc((size_t)N_NODES * D * 2);
    _Float16* Wt1   = (_Float16*)alloc((size_t)3 * D * D * 2);
    _Float16* Wt2   = (_Float16*)alloc((size_t)3 * D * D * 2);
    int*   slots   = (int*)alloc(((size_t)N_NODES * CAP + 64) * 4);  // +pad for s_load overrun
    int*   cnt     = (int*)alloc((size_t)N_NODES * 4);
    if (off > ws_size) return;

    hipMemsetAsync(cnt, 0, (size_t)N_NODES * 4, stream);

    gin_prep_kernel<<<PREP_E_BLOCKS + PREP_X_BLOCKS + PREP_W_BLOCKS, 256, 0, stream>>>(
        x, x_h, esrc, edst, cnt, slots, W1, W2, Wt1, Wt2);

    const int GLAYER = (N_NODES + 31) / 32;   // 1563 blocks, 32 nodes each

    // ping-pong: layer reads one buffer, writes the other
    const _Float16* lin[3]  = {x_h,  bufA, bufB};
    _Float16*       lout[3] = {bufA, bufB, bufA};
    for (int l = 0; l < 3; ++l) {
        gin_layer_kernel<<<GLAYER, 512, 0, stream>>>(
            lin[l], cnt, slots,
            Wt1 + (size_t)l * D * D, b1 + l * D,
            Wt2 + (size_t)l * D * D, b2 + l * D,
            bns + l * D, bnb + l * D, bnm + l * D, bnv + l * D,
            lout[l], N_NODES);
    }

    gin_poolhead_kernel<<<N_GRAPHS, 128, 0, stream>>>(bufA, batch, Wh1, bh1, Wh2, bh2, outp, N_NODES);
}